// Round 8
// baseline (787.615 us; speedup 1.0000x reference)
//
#include <hip/hip_runtime.h>
#include <math.h>

// Capsule dynamic routing, fused-recompute. fp32.
// B=512, R=1152, C=10, O=16, I=8.
//   iter0: c_ij = 1/10 uniform  -> s0 = 0.1 * sum_r u_hat
//   iter2: b2 = u.(v0+v1)       -> only running vsum kept
// R7 post-mortem: wall 65us vs ~26us VALU content; 2 waves/SIMD can't
// cover ds_read->FMA latency (occupancy is capped by TOTAL waves = work
// per thread, not LDS). R8: 512-thread blocks, waves 0-3 do r-half
// [0,9), waves 4-7 do [9,18) of the same rtile (own 2x15KB W buffers,
// 60KB total); epilogue LDS-combine of the two sacc halves; partials
// stay RT=64 (21MB, fits ws). Grid 512 = 2 blocks/CU = 16 waves/CU =
// 4 waves/SIMD (2x R7). launch_bounds(512,4) caps VGPR at 128 (=R7's
// count, no spill). oq-reduce shfl_xor(1/2) -> DPP quad_perm (VALU pipe,
// off the LDS pipe). XCD-chunked swizzle kept.

#define R_TOT 1152
#define C_N 10
#define O_N 16
#define I_N 8
#define B_TOT 512
#define RT 64                                   // rtile count (partial slices)
#define RCHB 18                                 // r's per rtile
#define HR 9                                    // r's per half
#define CHUNK 3                                 // r's per staged chunk
#define NCH 3                                   // chunks per half
#define SEG (B_TOT * C_N * O_N)                 // 81920 floats per partial slice
#define XT_ELEMS ((size_t)B_TOT * R_TOT * I_N * RCHB / RCHB)  // placeholder, unused
#define XT_FLOATS ((size_t)B_TOT * R_TOT * I_N) // 4,718,592 floats (18.9 MB)
#define WSLAB (C_N * O_N * I_N)                 // 1280 floats per r
#define GRAN (WSLAB / 4)                        // 320 float4 granules per r
#define CG (CHUNK * GRAN)                       // 960 granules per chunk

// granule swizzle within a slab: XOR bits[2:0] with bits[5:3] (involution).
__device__ __forceinline__ int swz(int g) { return g ^ ((g >> 3) & 7); }

// quad_perm DPP cross-lane adds (VALU pipe, not LDS): xor1 / xor2 over oq.
__device__ __forceinline__ float quad_add1(float v) {
  return v + __int_as_float(__builtin_amdgcn_update_dpp(
      0, __float_as_int(v), 0xB1 /*[1,0,3,2]*/, 0xF, 0xF, true));
}
__device__ __forceinline__ float quad_add2(float v) {
  return v + __int_as_float(__builtin_amdgcn_update_dpp(
      0, __float_as_int(v), 0x4E /*[2,3,0,1]*/, 0xF, 0xF, true));
}

// x[b][r][i] -> x_t[r][b][i]
__global__ __launch_bounds__(256) void transpose_x(
    const float* __restrict__ x, float* __restrict__ xt)
{
  const int t = blockIdx.x * 256 + threadIdx.x;   // t = b*R_TOT + r
  const int b = t / R_TOT;
  const int r = t - b * R_TOT;
  const float4* src = reinterpret_cast<const float4*>(x) + (size_t)t * 2;
  float4* dst = reinterpret_cast<float4*>(xt) + ((size_t)r * B_TOT + b) * 2;
  dst[0] = src[0];
  dst[1] = src[1];
}

// one r-step: u = W.x for this thread's (5c x 4o x 2b), then routing update.
template<bool UNIFORM>
__device__ __forceinline__ void body(
    const float4* const (&A)[8], int slab,     // granule offset within half
    const float (&xc)[2][8],
    const float (&vf)[5][2][4],
    float (&sacc)[5][2][4])
{
  float u[5][2][4];
  #pragma unroll
  for (int cc = 0; cc < 5; ++cc) {
    #pragma unroll
    for (int jo = 0; jo < 4; ++jo) {
      const float4 w0 = A[(2 * jo)     ^ ((cc & 1) << 2)][slab + cc * 32];
      const float4 w1 = A[(2 * jo + 1) ^ ((cc & 1) << 2)][slab + cc * 32];
      #pragma unroll
      for (int k = 0; k < 2; ++k) {
        u[cc][k][jo] =
            w0.x * xc[k][0] + w0.y * xc[k][1] + w0.z * xc[k][2] + w0.w * xc[k][3]
          + w1.x * xc[k][4] + w1.y * xc[k][5] + w1.z * xc[k][6] + w1.w * xc[k][7];
      }
    }
  }

  if constexpr (UNIFORM) {
    #pragma unroll
    for (int cc = 0; cc < 5; ++cc)
      #pragma unroll
      for (int k = 0; k < 2; ++k)
        #pragma unroll
        for (int jo = 0; jo < 4; ++jo)
          sacc[cc][k][jo] += u[cc][k][jo];
  } else {
    float bij[5][2];
    #pragma unroll
    for (int cc = 0; cc < 5; ++cc) {
      #pragma unroll
      for (int k = 0; k < 2; ++k) {
        float a = u[cc][k][0] * vf[cc][k][0] + u[cc][k][1] * vf[cc][k][1]
                + u[cc][k][2] * vf[cc][k][2] + u[cc][k][3] * vf[cc][k][3];
        a = quad_add1(a);        // + lane^1  (oq)
        a = quad_add2(a);        // + lane^2  (oq)
        bij[cc][k] = a;
      }
    }
    #pragma unroll
    for (int k = 0; k < 2; ++k) {
      float m = bij[0][k];
      #pragma unroll
      for (int cc = 1; cc < 5; ++cc) m = fmaxf(m, bij[cc][k]);
      m = fmaxf(m, __shfl_xor(m, 4));
      float e[5];
      float den = 0.0f;
      #pragma unroll
      for (int cc = 0; cc < 5; ++cc) { e[cc] = __expf(bij[cc][k] - m); den += e[cc]; }
      den += __shfl_xor(den, 4);
      const float inv = __builtin_amdgcn_rcpf(den);
      #pragma unroll
      for (int cc = 0; cc < 5; ++cc) {
        const float cw = e[cc] * inv;
        #pragma unroll
        for (int jo = 0; jo < 4; ++jo)
          sacc[cc][k][jo] += cw * u[cc][k][jo];
      }
    }
  }
}

// lane map (within a 256-thread half): oq = lane&3, ch = (lane>>2)&1,
// bl = lane>>3; thread owns b0 = btile*64 + wave*16 + bl*2 (+k),
// c = ch*5+cc, o = oq*4+jo. half = tid>>8 processes r in
// [rtile*18 + half*9, +9) as 3 double-buffered chunks of 3.
// grid: 512 blocks; XCD swizzle: xcd = bid&7 owns rtiles [xcd*8, xcd*8+8).
template<bool UNIFORM>
__global__ __launch_bounds__(512, 4) void acc_kernel(
    const float* __restrict__ xt, const float* __restrict__ W,
    const float* __restrict__ vsum, float* __restrict__ part)
{
  __shared__ float4 wbuf[2 * 2 * CG];   // [half][buf][960] = 60 KB

  const int tid  = threadIdx.x;         // 0..511
  const int half = tid >> 8;
  const int t    = tid & 255;
  const int wave = t >> 6;
  const int lane = t & 63;
  const int oq   = lane & 3;
  const int ch   = (lane >> 2) & 1;
  const int bl   = lane >> 3;

  const int bid   = blockIdx.x;
  const int xcd   = bid & 7;
  const int idx   = bid >> 3;           // 0..63
  const int rtile = xcd * 8 + (idx & 7);
  const int btile = idx >> 3;           // 0..7

  const int b0 = btile * 64 + wave * 16 + bl * 2;
  const int r0 = rtile * RCHB + half * HR;

  auto stage = [&](int ci, int buf) {
    const float4* wc = reinterpret_cast<const float4*>(W)
                     + (size_t)(r0 + ci * CHUNK) * GRAN;
    float4* dst = &wbuf[(half * 2 + buf) * CG];
    #pragma unroll
    for (int s = 0; s < CHUNK; ++s) {
      dst[s * GRAN + swz(t)] = wc[s * GRAN + t];
      if (t < GRAN - 256)
        dst[s * GRAN + swz(t + 256)] = wc[s * GRAN + t + 256];
    }
  };

  auto xload = [&](int r, float (&dst)[2][8]) {
    const float4* xp = reinterpret_cast<const float4*>(xt) + ((size_t)r * B_TOT + b0) * 2;
    #pragma unroll
    for (int k = 0; k < 2; ++k) {
      const float4 a = xp[2 * k], b = xp[2 * k + 1];
      dst[k][0] = a.x; dst[k][1] = a.y; dst[k][2] = a.z; dst[k][3] = a.w;
      dst[k][4] = b.x; dst[k][5] = b.y; dst[k][6] = b.z; dst[k][7] = b.w;
    }
  };

  // 8 swizzled LDS base pointers (granule units) within this half
  const int xv = (ch << 2) | oq;
  const float4* A[8];
  #pragma unroll
  for (int j = 0; j < 8; ++j)
    A[j] = &wbuf[half * 2 * CG + ch * 160 + oq * 8 + (j ^ xv)];

  float vf[5][2][4];
  if constexpr (!UNIFORM) {
    #pragma unroll
    for (int cc = 0; cc < 5; ++cc)
      #pragma unroll
      for (int k = 0; k < 2; ++k) {
        const float4 tv = *reinterpret_cast<const float4*>(
            &vsum[((b0 + k) * C_N + ch * 5 + cc) * O_N + oq * 4]);
        vf[cc][k][0] = tv.x; vf[cc][k][1] = tv.y; vf[cc][k][2] = tv.z; vf[cc][k][3] = tv.w;
      }
  }

  float sacc[5][2][4];
  #pragma unroll
  for (int cc = 0; cc < 5; ++cc)
    #pragma unroll
    for (int k = 0; k < 2; ++k)
      #pragma unroll
      for (int jo = 0; jo < 4; ++jo) sacc[cc][k][jo] = 0.0f;

  float xc[2][8], xn[2][8];
  stage(0, 0);
  xload(r0, xc);
  __syncthreads();

  #pragma unroll 1
  for (int ci = 0; ci < NCH; ++ci) {
    if (ci + 1 < NCH) stage(ci + 1, (ci + 1) & 1);
    const int sb = (ci & 1) * CG;
    #pragma unroll
    for (int rr = 0; rr < CHUNK; ++rr) {
      const int rl = ci * CHUNK + rr;
      const int rn = (rl + 1 < HR) ? rl + 1 : rl;
      xload(r0 + rn, xn);                 // prefetch next x under compute
      body<UNIFORM>(A, sb + rr * GRAN, xc, vf, sacc);
      #pragma unroll
      for (int k = 0; k < 2; ++k)
        #pragma unroll
        for (int i = 0; i < 8; ++i) xc[k][i] = xn[k][i];
    }
    __syncthreads();
  }

  // combine halves: half1 -> LDS (40KB, reuses wbuf), half0 adds + stores
  float* cbuf = reinterpret_cast<float*>(wbuf);
  if (half == 1) {
    #pragma unroll
    for (int cc = 0; cc < 5; ++cc)
      #pragma unroll
      for (int k = 0; k < 2; ++k)
        #pragma unroll
        for (int jo = 0; jo < 4; ++jo)
          cbuf[t * 40 + (cc * 2 + k) * 4 + jo] = sacc[cc][k][jo];
  }
  __syncthreads();
  if (half == 0) {
    const float scale = UNIFORM ? 0.1f : 1.0f;
    float* pb = part + (size_t)rtile * SEG;
    #pragma unroll
    for (int cc = 0; cc < 5; ++cc)
      #pragma unroll
      for (int k = 0; k < 2; ++k) {
        float4 v;
        v.x = (sacc[cc][k][0] + cbuf[t * 40 + (cc * 2 + k) * 4 + 0]) * scale;
        v.y = (sacc[cc][k][1] + cbuf[t * 40 + (cc * 2 + k) * 4 + 1]) * scale;
        v.z = (sacc[cc][k][2] + cbuf[t * 40 + (cc * 2 + k) * 4 + 2]) * scale;
        v.w = (sacc[cc][k][3] + cbuf[t * 40 + (cc * 2 + k) * 4 + 3]) * scale;
        *reinterpret_cast<float4*>(
            &pb[((b0 + k) * C_N + ch * 5 + cc) * O_N + oq * 4]) = v;
      }
  }
}

// reduce over rtiles + squash over O=16 per (b,c). grid = SEG/64 blocks.
// MODE 0: vsum = v ; MODE 1: vsum += v ; MODE 2: out = v
template<int MODE>
__global__ __launch_bounds__(256) void reduce_squash(
    const float* __restrict__ part, int nrt,
    float* __restrict__ vsum, float* __restrict__ out)
{
  __shared__ float lds[4][64];
  const int tid = threadIdx.x;
  const int l   = tid & 63;
  const int q   = tid >> 6;
  const int j   = blockIdx.x * 64 + l;
  const float* p = part + j;
  float sv = 0.0f;
  #pragma unroll 4
  for (int rt = q; rt < nrt; rt += 4) sv += p[(size_t)rt * SEG];
  lds[q][l] = sv;
  __syncthreads();
  if (q == 0) {
    sv = lds[0][l] + lds[1][l] + lds[2][l] + lds[3][l];
    float sq = sv * sv;
    sq += __shfl_xor(sq, 1);
    sq += __shfl_xor(sq, 2);
    sq += __shfl_xor(sq, 4);
    sq += __shfl_xor(sq, 8);
    const float scale = sq / (1.0f + sq) * rsqrtf(sq + 1e-8f);
    const float v = scale * sv;
    if constexpr (MODE == 0)      vsum[j] = v;
    else if constexpr (MODE == 1) vsum[j] += v;
    else                          out[j] = v;
  }
}

extern "C" void kernel_launch(void* const* d_in, const int* in_sizes, int n_in,
                              void* d_out, int out_size, void* d_ws, size_t ws_size,
                              hipStream_t stream) {
  (void)in_sizes; (void)n_in; (void)out_size; (void)ws_size;
  const float* x = (const float*)d_in[0];
  const float* W = (const float*)d_in[1];
  float* out  = (float*)d_out;   // doubles as vsum; fully rewritten with v2
  float* part = (float*)d_ws;    // RT * SEG floats = 21 MB
  float* xt   = part + (size_t)RT * SEG;   // 18.9 MB (total 40 MB < ws)

  const dim3 blk256(256), blk512(512), accGrid(8 * RT), sqGrid(SEG / 64);

  hipLaunchKernelGGL(transpose_x, dim3((B_TOT * R_TOT) / 256), blk256, 0, stream, x, xt);

  // iter 0: uniform coefficients (softmax of zeros)
  hipLaunchKernelGGL((acc_kernel<true>),  accGrid, blk512, 0, stream, xt, W, out, part);
  hipLaunchKernelGGL((reduce_squash<0>),  sqGrid,  blk256, 0, stream, part, RT, out, out);  // vsum = v0
  // iter 1
  hipLaunchKernelGGL((acc_kernel<false>), accGrid, blk512, 0, stream, xt, W, out, part);
  hipLaunchKernelGGL((reduce_squash<1>),  sqGrid,  blk256, 0, stream, part, RT, out, out);  // vsum = v0+v1
  // iter 2
  hipLaunchKernelGGL((acc_kernel<false>), accGrid, blk512, 0, stream, xt, W, out, part);
  hipLaunchKernelGGL((reduce_squash<2>),  sqGrid,  blk256, 0, stream, part, RT, out, out);  // out = v2
}

// Round 9
// 723.233 us; speedup vs baseline: 1.0890x; 1.0890x over previous
//
#include <hip/hip_runtime.h>
#include <math.h>

// Capsule dynamic routing, fused-recompute. fp32.
// B=512, R=1152, C=10, O=16, I=8.
//   iter0: c_ij = 1/10 uniform  -> s0 = 0.1 * sum_r u_hat
//   iter2: b2 = u.(v0+v1)       -> only running vsum kept
// R8 post-mortem: launch_bounds(512,4) drove the allocator to 64 VGPRs,
// spilling ~112 floats of state (390MB fetch + 574MB write of scratch).
// R9: R7's proven 256-thread body (fit 128 VGPRs) with DOUBLED grid:
// 1024 blocks x 9 r's each; LDS halves to 30KB (2 x 3-slab buffers)
// -> 4 blocks/CU exact = 16 waves/CU = 4 waves/SIMD (2x R7's TLP).
// Partials double to 128 slices (41.9MB; ws >= 50.4MB proven in R6),
// so xt is dropped: x read in natural layout, prefetched one r ahead
// (off critical path), and per-XCD working set (720KB W + 2.3MB x) is
// L2-resident via XCD-chunked swizzle. launch_bounds(256,4) = cap 128
// = exactly R7's measured usage.

#define R_TOT 1152
#define C_N 10
#define O_N 16
#define I_N 8
#define B_TOT 512
#define RSLOTS 128                              // partial slices (r-slots)
#define RCHB 9                                  // r's per block
#define CHUNK 3                                 // r's per staged chunk
#define NCH 3                                   // chunks per block
#define SEG (B_TOT * C_N * O_N)                 // 81920 floats per partial slice
#define WSLAB (C_N * O_N * I_N)                 // 1280 floats per r
#define GRAN (WSLAB / 4)                        // 320 float4 granules per r
#define CG (CHUNK * GRAN)                       // 960 granules per chunk

// granule swizzle within a slab: XOR bits[2:0] with bits[5:3] (involution).
__device__ __forceinline__ int swz(int g) { return g ^ ((g >> 3) & 7); }

// quad_perm DPP cross-lane adds (VALU pipe, not LDS): xor1 / xor2 over oq.
__device__ __forceinline__ float quad_add1(float v) {
  return v + __int_as_float(__builtin_amdgcn_update_dpp(
      0, __float_as_int(v), 0xB1 /*[1,0,3,2]*/, 0xF, 0xF, true));
}
__device__ __forceinline__ float quad_add2(float v) {
  return v + __int_as_float(__builtin_amdgcn_update_dpp(
      0, __float_as_int(v), 0x4E /*[2,3,0,1]*/, 0xF, 0xF, true));
}

// one r-step: u = W.x for this thread's (5c x 4o x 2b), then routing update.
template<bool UNIFORM>
__device__ __forceinline__ void body(
    const float4* const (&A)[8], int slab,     // granule offset (runtime)
    const float (&xc)[2][8],
    const float (&vf)[5][2][4],
    float (&sacc)[5][2][4])
{
  float u[5][2][4];
  #pragma unroll
  for (int cc = 0; cc < 5; ++cc) {
    #pragma unroll
    for (int jo = 0; jo < 4; ++jo) {
      const float4 w0 = A[(2 * jo)     ^ ((cc & 1) << 2)][slab + cc * 32];
      const float4 w1 = A[(2 * jo + 1) ^ ((cc & 1) << 2)][slab + cc * 32];
      #pragma unroll
      for (int k = 0; k < 2; ++k) {
        u[cc][k][jo] =
            w0.x * xc[k][0] + w0.y * xc[k][1] + w0.z * xc[k][2] + w0.w * xc[k][3]
          + w1.x * xc[k][4] + w1.y * xc[k][5] + w1.z * xc[k][6] + w1.w * xc[k][7];
      }
    }
  }

  if constexpr (UNIFORM) {
    #pragma unroll
    for (int cc = 0; cc < 5; ++cc)
      #pragma unroll
      for (int k = 0; k < 2; ++k)
        #pragma unroll
        for (int jo = 0; jo < 4; ++jo)
          sacc[cc][k][jo] += u[cc][k][jo];
  } else {
    float bij[5][2];
    #pragma unroll
    for (int cc = 0; cc < 5; ++cc) {
      #pragma unroll
      for (int k = 0; k < 2; ++k) {
        float a = u[cc][k][0] * vf[cc][k][0] + u[cc][k][1] * vf[cc][k][1]
                + u[cc][k][2] * vf[cc][k][2] + u[cc][k][3] * vf[cc][k][3];
        a = quad_add1(a);        // + lane^1  (oq)
        a = quad_add2(a);        // + lane^2  (oq)
        bij[cc][k] = a;
      }
    }
    #pragma unroll
    for (int k = 0; k < 2; ++k) {
      float m = bij[0][k];
      #pragma unroll
      for (int cc = 1; cc < 5; ++cc) m = fmaxf(m, bij[cc][k]);
      m = fmaxf(m, __shfl_xor(m, 4));
      float e[5];
      float den = 0.0f;
      #pragma unroll
      for (int cc = 0; cc < 5; ++cc) { e[cc] = __expf(bij[cc][k] - m); den += e[cc]; }
      den += __shfl_xor(den, 4);
      const float inv = __builtin_amdgcn_rcpf(den);
      #pragma unroll
      for (int cc = 0; cc < 5; ++cc) {
        const float cw = e[cc] * inv;
        #pragma unroll
        for (int jo = 0; jo < 4; ++jo)
          sacc[cc][k][jo] += cw * u[cc][k][jo];
      }
    }
  }
}

// lane map: oq = lane&3, ch = (lane>>2)&1, bl = lane>>3; thread owns
// b0 = btile*64 + wave*16 + bl*2 (+k), c = ch*5+cc, o = oq*4+jo.
// grid 1024: xcd = bid&7, idx = bid>>3; rslot = xcd*16 + (idx&15),
// btile = idx>>4. Each XCD owns 16 contiguous rslots (720KB W + 2.3MB x
// working set, L2-resident).
template<bool UNIFORM>
__global__ __launch_bounds__(256, 4) void acc_kernel(
    const float* __restrict__ x, const float* __restrict__ W,
    const float* __restrict__ vsum, float* __restrict__ part)
{
  __shared__ float4 wbuf[2 * CG];   // 30 KB: two 3-slab chunks

  const int tid  = threadIdx.x;
  const int wave = tid >> 6;
  const int lane = tid & 63;
  const int oq   = lane & 3;
  const int ch   = (lane >> 2) & 1;
  const int bl   = lane >> 3;

  const int bid   = blockIdx.x;
  const int xcd   = bid & 7;
  const int idx   = bid >> 3;             // 0..127
  const int rslot = xcd * 16 + (idx & 15);
  const int btile = idx >> 4;             // 0..7

  const int b0 = btile * 64 + wave * 16 + bl * 2;
  const int r0 = rslot * RCHB;

  auto stage = [&](int ci, int buf) {
    const float4* wc = reinterpret_cast<const float4*>(W)
                     + (size_t)(r0 + ci * CHUNK) * GRAN;
    float4* dst = &wbuf[buf * CG];
    #pragma unroll
    for (int s = 0; s < CHUNK; ++s) {
      dst[s * GRAN + swz(tid)] = wc[s * GRAN + tid];
      if (tid < GRAN - 256)
        dst[s * GRAN + swz(tid + 256)] = wc[s * GRAN + tid + 256];
    }
  };

  // natural-layout x: 2 float4s per owned b; prefetched one r ahead.
  auto xload = [&](int r, float (&dst)[2][8]) {
    #pragma unroll
    for (int k = 0; k < 2; ++k) {
      const float4* xp = reinterpret_cast<const float4*>(x)
                       + ((size_t)(b0 + k) * R_TOT + r) * 2;
      const float4 a = xp[0], b = xp[1];
      dst[k][0] = a.x; dst[k][1] = a.y; dst[k][2] = a.z; dst[k][3] = a.w;
      dst[k][4] = b.x; dst[k][5] = b.y; dst[k][6] = b.z; dst[k][7] = b.w;
    }
  };

  // 8 swizzled LDS base pointers (granule units): ch*160 + oq*8 + (j ^ xv)
  const int xv = (ch << 2) | oq;
  const float4* A[8];
  #pragma unroll
  for (int j = 0; j < 8; ++j)
    A[j] = &wbuf[ch * 160 + oq * 8 + (j ^ xv)];

  float vf[5][2][4];
  if constexpr (!UNIFORM) {
    #pragma unroll
    for (int cc = 0; cc < 5; ++cc)
      #pragma unroll
      for (int k = 0; k < 2; ++k) {
        const float4 tv = *reinterpret_cast<const float4*>(
            &vsum[((b0 + k) * C_N + ch * 5 + cc) * O_N + oq * 4]);
        vf[cc][k][0] = tv.x; vf[cc][k][1] = tv.y; vf[cc][k][2] = tv.z; vf[cc][k][3] = tv.w;
      }
  }

  float sacc[5][2][4];
  #pragma unroll
  for (int cc = 0; cc < 5; ++cc)
    #pragma unroll
    for (int k = 0; k < 2; ++k)
      #pragma unroll
      for (int jo = 0; jo < 4; ++jo) sacc[cc][k][jo] = 0.0f;

  float xc[2][8], xn[2][8];
  stage(0, 0);
  xload(r0, xc);
  __syncthreads();

  #pragma unroll 1
  for (int ci = 0; ci < NCH; ++ci) {
    if (ci + 1 < NCH) stage(ci + 1, (ci + 1) & 1);
    const int sb = (ci & 1) * CG;
    #pragma unroll
    for (int rr = 0; rr < CHUNK; ++rr) {
      const int rl = ci * CHUNK + rr;
      const int rn = (rl + 1 < RCHB) ? rl + 1 : rl;
      xload(r0 + rn, xn);                 // prefetch next x under compute
      body<UNIFORM>(A, sb + rr * GRAN, xc, vf, sacc);
      #pragma unroll
      for (int k = 0; k < 2; ++k)
        #pragma unroll
        for (int i = 0; i < 8; ++i) xc[k][i] = xn[k][i];
    }
    __syncthreads();
  }

  const float scale = UNIFORM ? 0.1f : 1.0f;
  float* pb = part + (size_t)rslot * SEG;
  #pragma unroll
  for (int cc = 0; cc < 5; ++cc)
    #pragma unroll
    for (int k = 0; k < 2; ++k) {
      float4 v;
      v.x = sacc[cc][k][0] * scale; v.y = sacc[cc][k][1] * scale;
      v.z = sacc[cc][k][2] * scale; v.w = sacc[cc][k][3] * scale;
      *reinterpret_cast<float4*>(
          &pb[((b0 + k) * C_N + ch * 5 + cc) * O_N + oq * 4]) = v;
    }
}

// reduce over rslots + squash over O=16 per (b,c). grid = SEG/64 blocks.
// MODE 0: vsum = v ; MODE 1: vsum += v ; MODE 2: out = v
template<int MODE>
__global__ __launch_bounds__(256) void reduce_squash(
    const float* __restrict__ part, int nrt,
    float* __restrict__ vsum, float* __restrict__ out)
{
  __shared__ float lds[4][64];
  const int tid = threadIdx.x;
  const int l   = tid & 63;
  const int q   = tid >> 6;
  const int j   = blockIdx.x * 64 + l;
  const float* p = part + j;
  float sv = 0.0f;
  #pragma unroll 4
  for (int rt = q; rt < nrt; rt += 4) sv += p[(size_t)rt * SEG];
  lds[q][l] = sv;
  __syncthreads();
  if (q == 0) {
    sv = lds[0][l] + lds[1][l] + lds[2][l] + lds[3][l];
    float sq = sv * sv;
    sq += __shfl_xor(sq, 1);
    sq += __shfl_xor(sq, 2);
    sq += __shfl_xor(sq, 4);
    sq += __shfl_xor(sq, 8);
    const float scale = sq / (1.0f + sq) * rsqrtf(sq + 1e-8f);
    const float v = scale * sv;
    if constexpr (MODE == 0)      vsum[j] = v;
    else if constexpr (MODE == 1) vsum[j] += v;
    else                          out[j] = v;
  }
}

extern "C" void kernel_launch(void* const* d_in, const int* in_sizes, int n_in,
                              void* d_out, int out_size, void* d_ws, size_t ws_size,
                              hipStream_t stream) {
  (void)in_sizes; (void)n_in; (void)out_size; (void)ws_size;
  const float* x = (const float*)d_in[0];
  const float* W = (const float*)d_in[1];
  float* out  = (float*)d_out;   // doubles as vsum; fully rewritten with v2
  float* part = (float*)d_ws;    // RSLOTS * SEG floats = 41.9 MB (ws >= 50.4 MB)

  const dim3 blk(256), accGrid(8 * RSLOTS), sqGrid(SEG / 64);

  // iter 0: uniform coefficients (softmax of zeros)
  hipLaunchKernelGGL((acc_kernel<true>),  accGrid, blk, 0, stream, x, W, out, part);
  hipLaunchKernelGGL((reduce_squash<0>),  sqGrid,  blk, 0, stream, part, RSLOTS, out, out);  // vsum = v0
  // iter 1
  hipLaunchKernelGGL((acc_kernel<false>), accGrid, blk, 0, stream, x, W, out, part);
  hipLaunchKernelGGL((reduce_squash<1>),  sqGrid,  blk, 0, stream, part, RSLOTS, out, out);  // vsum = v0+v1
  // iter 2
  hipLaunchKernelGGL((acc_kernel<false>), accGrid, blk, 0, stream, x, W, out, part);
  hipLaunchKernelGGL((reduce_squash<2>),  sqGrid,  blk, 0, stream, part, RSLOTS, out, out);  // out = v2
}

// Round 10
// 266.446 us; speedup vs baseline: 2.9560x; 2.7144x over previous
//
#include <hip/hip_runtime.h>
#include <math.h>

// Capsule dynamic routing, fused-recompute. fp32.
// B=512, R=1152, C=10, O=16, I=8.
//   iter0: c_ij = 1/10 uniform  -> s0 = 0.1 * sum_r u_hat
//   iter2: b2 = u.(v0+v1)       -> only running vsum kept
// R9 post-mortem: __launch_bounds__(...,4) forces a 64-VGPR tier on this
// compiler (R8 AND R9 both hit it) -> ~112 live floats spill -> 395MB
// fetch + 546MB write of scratch, VALUBusy 10%. The second arg is only a
// regalloc floor; runtime occupancy = min(VGPR,LDS) limits. With VGPR=128
// (16 waves/CU) and LDS=30KB (5 blocks), HW already runs 4 blocks/CU.
// R10: R9 structure verbatim (1024 blocks x 9 r, 30KB LDS, XCD swizzle,
// natural-x prefetch) with launch_bounds(256,2) — the combo R7 measured
// at exactly 128 VGPRs, zero spill.

#define R_TOT 1152
#define C_N 10
#define O_N 16
#define I_N 8
#define B_TOT 512
#define RSLOTS 128                              // partial slices (r-slots)
#define RCHB 9                                  // r's per block
#define CHUNK 3                                 // r's per staged chunk
#define NCH 3                                   // chunks per block
#define SEG (B_TOT * C_N * O_N)                 // 81920 floats per partial slice
#define WSLAB (C_N * O_N * I_N)                 // 1280 floats per r
#define GRAN (WSLAB / 4)                        // 320 float4 granules per r
#define CG (CHUNK * GRAN)                       // 960 granules per chunk

// granule swizzle within a slab: XOR bits[2:0] with bits[5:3] (involution).
__device__ __forceinline__ int swz(int g) { return g ^ ((g >> 3) & 7); }

// quad_perm DPP cross-lane adds (VALU pipe, not LDS): xor1 / xor2 over oq.
__device__ __forceinline__ float quad_add1(float v) {
  return v + __int_as_float(__builtin_amdgcn_update_dpp(
      0, __float_as_int(v), 0xB1 /*[1,0,3,2]*/, 0xF, 0xF, true));
}
__device__ __forceinline__ float quad_add2(float v) {
  return v + __int_as_float(__builtin_amdgcn_update_dpp(
      0, __float_as_int(v), 0x4E /*[2,3,0,1]*/, 0xF, 0xF, true));
}

// one r-step: u = W.x for this thread's (5c x 4o x 2b), then routing update.
template<bool UNIFORM>
__device__ __forceinline__ void body(
    const float4* const (&A)[8], int slab,     // granule offset (runtime)
    const float (&xc)[2][8],
    const float (&vf)[5][2][4],
    float (&sacc)[5][2][4])
{
  float u[5][2][4];
  #pragma unroll
  for (int cc = 0; cc < 5; ++cc) {
    #pragma unroll
    for (int jo = 0; jo < 4; ++jo) {
      const float4 w0 = A[(2 * jo)     ^ ((cc & 1) << 2)][slab + cc * 32];
      const float4 w1 = A[(2 * jo + 1) ^ ((cc & 1) << 2)][slab + cc * 32];
      #pragma unroll
      for (int k = 0; k < 2; ++k) {
        u[cc][k][jo] =
            w0.x * xc[k][0] + w0.y * xc[k][1] + w0.z * xc[k][2] + w0.w * xc[k][3]
          + w1.x * xc[k][4] + w1.y * xc[k][5] + w1.z * xc[k][6] + w1.w * xc[k][7];
      }
    }
  }

  if constexpr (UNIFORM) {
    #pragma unroll
    for (int cc = 0; cc < 5; ++cc)
      #pragma unroll
      for (int k = 0; k < 2; ++k)
        #pragma unroll
        for (int jo = 0; jo < 4; ++jo)
          sacc[cc][k][jo] += u[cc][k][jo];
  } else {
    float bij[5][2];
    #pragma unroll
    for (int cc = 0; cc < 5; ++cc) {
      #pragma unroll
      for (int k = 0; k < 2; ++k) {
        float a = u[cc][k][0] * vf[cc][k][0] + u[cc][k][1] * vf[cc][k][1]
                + u[cc][k][2] * vf[cc][k][2] + u[cc][k][3] * vf[cc][k][3];
        a = quad_add1(a);        // + lane^1  (oq)
        a = quad_add2(a);        // + lane^2  (oq)
        bij[cc][k] = a;
      }
    }
    #pragma unroll
    for (int k = 0; k < 2; ++k) {
      float m = bij[0][k];
      #pragma unroll
      for (int cc = 1; cc < 5; ++cc) m = fmaxf(m, bij[cc][k]);
      m = fmaxf(m, __shfl_xor(m, 4));
      float e[5];
      float den = 0.0f;
      #pragma unroll
      for (int cc = 0; cc < 5; ++cc) { e[cc] = __expf(bij[cc][k] - m); den += e[cc]; }
      den += __shfl_xor(den, 4);
      const float inv = __builtin_amdgcn_rcpf(den);
      #pragma unroll
      for (int cc = 0; cc < 5; ++cc) {
        const float cw = e[cc] * inv;
        #pragma unroll
        for (int jo = 0; jo < 4; ++jo)
          sacc[cc][k][jo] += cw * u[cc][k][jo];
      }
    }
  }
}

// lane map: oq = lane&3, ch = (lane>>2)&1, bl = lane>>3; thread owns
// b0 = btile*64 + wave*16 + bl*2 (+k), c = ch*5+cc, o = oq*4+jo.
// grid 1024: xcd = bid&7, idx = bid>>3; rslot = xcd*16 + (idx&15),
// btile = idx>>4. Each XCD owns 16 contiguous rslots (720KB W + 2.3MB x
// working set, L2-resident).
template<bool UNIFORM>
__global__ __launch_bounds__(256, 2) void acc_kernel(
    const float* __restrict__ x, const float* __restrict__ W,
    const float* __restrict__ vsum, float* __restrict__ part)
{
  __shared__ float4 wbuf[2 * CG];   // 30 KB: two 3-slab chunks

  const int tid  = threadIdx.x;
  const int wave = tid >> 6;
  const int lane = tid & 63;
  const int oq   = lane & 3;
  const int ch   = (lane >> 2) & 1;
  const int bl   = lane >> 3;

  const int bid   = blockIdx.x;
  const int xcd   = bid & 7;
  const int idx   = bid >> 3;             // 0..127
  const int rslot = xcd * 16 + (idx & 15);
  const int btile = idx >> 4;             // 0..7

  const int b0 = btile * 64 + wave * 16 + bl * 2;
  const int r0 = rslot * RCHB;

  auto stage = [&](int ci, int buf) {
    const float4* wc = reinterpret_cast<const float4*>(W)
                     + (size_t)(r0 + ci * CHUNK) * GRAN;
    float4* dst = &wbuf[buf * CG];
    #pragma unroll
    for (int s = 0; s < CHUNK; ++s) {
      dst[s * GRAN + swz(tid)] = wc[s * GRAN + tid];
      if (tid < GRAN - 256)
        dst[s * GRAN + swz(tid + 256)] = wc[s * GRAN + tid + 256];
    }
  };

  // natural-layout x: 2 float4s per owned b; prefetched one r ahead.
  auto xload = [&](int r, float (&dst)[2][8]) {
    #pragma unroll
    for (int k = 0; k < 2; ++k) {
      const float4* xp = reinterpret_cast<const float4*>(x)
                       + ((size_t)(b0 + k) * R_TOT + r) * 2;
      const float4 a = xp[0], b = xp[1];
      dst[k][0] = a.x; dst[k][1] = a.y; dst[k][2] = a.z; dst[k][3] = a.w;
      dst[k][4] = b.x; dst[k][5] = b.y; dst[k][6] = b.z; dst[k][7] = b.w;
    }
  };

  // 8 swizzled LDS base pointers (granule units): ch*160 + oq*8 + (j ^ xv)
  const int xv = (ch << 2) | oq;
  const float4* A[8];
  #pragma unroll
  for (int j = 0; j < 8; ++j)
    A[j] = &wbuf[ch * 160 + oq * 8 + (j ^ xv)];

  float vf[5][2][4];
  if constexpr (!UNIFORM) {
    #pragma unroll
    for (int cc = 0; cc < 5; ++cc)
      #pragma unroll
      for (int k = 0; k < 2; ++k) {
        const float4 tv = *reinterpret_cast<const float4*>(
            &vsum[((b0 + k) * C_N + ch * 5 + cc) * O_N + oq * 4]);
        vf[cc][k][0] = tv.x; vf[cc][k][1] = tv.y; vf[cc][k][2] = tv.z; vf[cc][k][3] = tv.w;
      }
  }

  float sacc[5][2][4];
  #pragma unroll
  for (int cc = 0; cc < 5; ++cc)
    #pragma unroll
    for (int k = 0; k < 2; ++k)
      #pragma unroll
      for (int jo = 0; jo < 4; ++jo) sacc[cc][k][jo] = 0.0f;

  float xc[2][8], xn[2][8];
  stage(0, 0);
  xload(r0, xc);
  __syncthreads();

  #pragma unroll 1
  for (int ci = 0; ci < NCH; ++ci) {
    if (ci + 1 < NCH) stage(ci + 1, (ci + 1) & 1);
    const int sb = (ci & 1) * CG;
    #pragma unroll
    for (int rr = 0; rr < CHUNK; ++rr) {
      const int rl = ci * CHUNK + rr;
      const int rn = (rl + 1 < RCHB) ? rl + 1 : rl;
      xload(r0 + rn, xn);                 // prefetch next x under compute
      body<UNIFORM>(A, sb + rr * GRAN, xc, vf, sacc);
      #pragma unroll
      for (int k = 0; k < 2; ++k)
        #pragma unroll
        for (int i = 0; i < 8; ++i) xc[k][i] = xn[k][i];
    }
    __syncthreads();
  }

  const float scale = UNIFORM ? 0.1f : 1.0f;
  float* pb = part + (size_t)rslot * SEG;
  #pragma unroll
  for (int cc = 0; cc < 5; ++cc)
    #pragma unroll
    for (int k = 0; k < 2; ++k) {
      float4 v;
      v.x = sacc[cc][k][0] * scale; v.y = sacc[cc][k][1] * scale;
      v.z = sacc[cc][k][2] * scale; v.w = sacc[cc][k][3] * scale;
      *reinterpret_cast<float4*>(
          &pb[((b0 + k) * C_N + ch * 5 + cc) * O_N + oq * 4]) = v;
    }
}

// reduce over rslots + squash over O=16 per (b,c). grid = SEG/64 blocks.
// MODE 0: vsum = v ; MODE 1: vsum += v ; MODE 2: out = v
template<int MODE>
__global__ __launch_bounds__(256) void reduce_squash(
    const float* __restrict__ part, int nrt,
    float* __restrict__ vsum, float* __restrict__ out)
{
  __shared__ float lds[4][64];
  const int tid = threadIdx.x;
  const int l   = tid & 63;
  const int q   = tid >> 6;
  const int j   = blockIdx.x * 64 + l;
  const float* p = part + j;
  float sv = 0.0f;
  #pragma unroll 4
  for (int rt = q; rt < nrt; rt += 4) sv += p[(size_t)rt * SEG];
  lds[q][l] = sv;
  __syncthreads();
  if (q == 0) {
    sv = lds[0][l] + lds[1][l] + lds[2][l] + lds[3][l];
    float sq = sv * sv;
    sq += __shfl_xor(sq, 1);
    sq += __shfl_xor(sq, 2);
    sq += __shfl_xor(sq, 4);
    sq += __shfl_xor(sq, 8);
    const float scale = sq / (1.0f + sq) * rsqrtf(sq + 1e-8f);
    const float v = scale * sv;
    if constexpr (MODE == 0)      vsum[j] = v;
    else if constexpr (MODE == 1) vsum[j] += v;
    else                          out[j] = v;
  }
}

extern "C" void kernel_launch(void* const* d_in, const int* in_sizes, int n_in,
                              void* d_out, int out_size, void* d_ws, size_t ws_size,
                              hipStream_t stream) {
  (void)in_sizes; (void)n_in; (void)out_size; (void)ws_size;
  const float* x = (const float*)d_in[0];
  const float* W = (const float*)d_in[1];
  float* out  = (float*)d_out;   // doubles as vsum; fully rewritten with v2
  float* part = (float*)d_ws;    // RSLOTS * SEG floats = 41.9 MB

  const dim3 blk(256), accGrid(8 * RSLOTS), sqGrid(SEG / 64);

  // iter 0: uniform coefficients (softmax of zeros)
  hipLaunchKernelGGL((acc_kernel<true>),  accGrid, blk, 0, stream, x, W, out, part);
  hipLaunchKernelGGL((reduce_squash<0>),  sqGrid,  blk, 0, stream, part, RSLOTS, out, out);  // vsum = v0
  // iter 1
  hipLaunchKernelGGL((acc_kernel<false>), accGrid, blk, 0, stream, x, W, out, part);
  hipLaunchKernelGGL((reduce_squash<1>),  sqGrid,  blk, 0, stream, part, RSLOTS, out, out);  // vsum = v0+v1
  // iter 2
  hipLaunchKernelGGL((acc_kernel<false>), accGrid, blk, 0, stream, x, W, out, part);
  hipLaunchKernelGGL((reduce_squash<2>),  sqGrid,  blk, 0, stream, part, RSLOTS, out, out);  // out = v2
}

// Round 12
// 198.433 us; speedup vs baseline: 3.9692x; 1.3427x over previous
//
#include <hip/hip_runtime.h>
#include <math.h>

// Capsule dynamic routing, fused-recompute. fp32.
// B=512, R=1152, C=10, O=16, I=8.
//   iter0: c_ij = 1/10 uniform  -> s0 = 0.1 * sum_r u_hat
//   iter2: b2 = u.(v0+v1)       -> only running vsum kept
// R10 post-mortem: RT=128 partials (42MB, 5.2MB/XCD) thrash the 4MB
// per-XCD L2 via write-allocate eviction -> FETCH 15->120MB, acc 65->110us.
// R11/R12: R7 structure restored (xt + transpose, (256,2)=128 VGPR),
// RT=96 -> grid 768 = exactly 3 blocks/CU (12 waves/CU, 1.5x TLP),
// CHUNK=4 double-buffer = 40KB LDS, and NON-TEMPORAL partial stores so
// the 31MB partial stream doesn't evict W/x from L2. R12 fixes the
// compile error: __builtin_nontemporal_store needs a clang ext_vector
// type, not HIP's float4 class.

#define R_TOT 1152
#define C_N 10
#define O_N 16
#define I_N 8
#define B_TOT 512
#define RT 96                                   // rtile count (partial slices)
#define RCHB 12                                 // r's per block
#define CHUNK 4                                 // r's per staged chunk
#define NCH 3                                   // chunks per block
#define SEG (B_TOT * C_N * O_N)                 // 81920 floats per partial slice
#define XT_FLOATS ((size_t)B_TOT * R_TOT * I_N) // 4,718,592 floats (18.9 MB)
#define WSLAB (C_N * O_N * I_N)                 // 1280 floats per r
#define GRAN (WSLAB / 4)                        // 320 float4 granules per r
#define CG (CHUNK * GRAN)                       // 1280 granules per chunk

typedef float f32x4 __attribute__((ext_vector_type(4)));  // for nontemporal_store

// granule swizzle within a slab: XOR bits[2:0] with bits[5:3] (involution).
__device__ __forceinline__ int swz(int g) { return g ^ ((g >> 3) & 7); }

// quad_perm DPP cross-lane adds (VALU pipe, not LDS): xor1 / xor2 over oq.
__device__ __forceinline__ float quad_add1(float v) {
  return v + __int_as_float(__builtin_amdgcn_update_dpp(
      0, __float_as_int(v), 0xB1 /*[1,0,3,2]*/, 0xF, 0xF, true));
}
__device__ __forceinline__ float quad_add2(float v) {
  return v + __int_as_float(__builtin_amdgcn_update_dpp(
      0, __float_as_int(v), 0x4E /*[2,3,0,1]*/, 0xF, 0xF, true));
}

// x[b][r][i] -> x_t[r][b][i]
__global__ __launch_bounds__(256) void transpose_x(
    const float* __restrict__ x, float* __restrict__ xt)
{
  const int t = blockIdx.x * 256 + threadIdx.x;   // t = b*R_TOT + r
  const int b = t / R_TOT;
  const int r = t - b * R_TOT;
  const float4* src = reinterpret_cast<const float4*>(x) + (size_t)t * 2;
  float4* dst = reinterpret_cast<float4*>(xt) + ((size_t)r * B_TOT + b) * 2;
  dst[0] = src[0];
  dst[1] = src[1];
}

// one r-step: u = W.x for this thread's (5c x 4o x 2b), then routing update.
template<bool UNIFORM>
__device__ __forceinline__ void body(
    const float4* const (&A)[8], int slab,     // granule offset (runtime)
    const float (&xc)[2][8],
    const float (&vf)[5][2][4],
    float (&sacc)[5][2][4])
{
  float u[5][2][4];
  #pragma unroll
  for (int cc = 0; cc < 5; ++cc) {
    #pragma unroll
    for (int jo = 0; jo < 4; ++jo) {
      const float4 w0 = A[(2 * jo)     ^ ((cc & 1) << 2)][slab + cc * 32];
      const float4 w1 = A[(2 * jo + 1) ^ ((cc & 1) << 2)][slab + cc * 32];
      #pragma unroll
      for (int k = 0; k < 2; ++k) {
        u[cc][k][jo] =
            w0.x * xc[k][0] + w0.y * xc[k][1] + w0.z * xc[k][2] + w0.w * xc[k][3]
          + w1.x * xc[k][4] + w1.y * xc[k][5] + w1.z * xc[k][6] + w1.w * xc[k][7];
      }
    }
  }

  if constexpr (UNIFORM) {
    #pragma unroll
    for (int cc = 0; cc < 5; ++cc)
      #pragma unroll
      for (int k = 0; k < 2; ++k)
        #pragma unroll
        for (int jo = 0; jo < 4; ++jo)
          sacc[cc][k][jo] += u[cc][k][jo];
  } else {
    float bij[5][2];
    #pragma unroll
    for (int cc = 0; cc < 5; ++cc) {
      #pragma unroll
      for (int k = 0; k < 2; ++k) {
        float a = u[cc][k][0] * vf[cc][k][0] + u[cc][k][1] * vf[cc][k][1]
                + u[cc][k][2] * vf[cc][k][2] + u[cc][k][3] * vf[cc][k][3];
        a = quad_add1(a);        // + lane^1  (oq)
        a = quad_add2(a);        // + lane^2  (oq)
        bij[cc][k] = a;
      }
    }
    #pragma unroll
    for (int k = 0; k < 2; ++k) {
      float m = bij[0][k];
      #pragma unroll
      for (int cc = 1; cc < 5; ++cc) m = fmaxf(m, bij[cc][k]);
      m = fmaxf(m, __shfl_xor(m, 4));
      float e[5];
      float den = 0.0f;
      #pragma unroll
      for (int cc = 0; cc < 5; ++cc) { e[cc] = __expf(bij[cc][k] - m); den += e[cc]; }
      den += __shfl_xor(den, 4);
      const float inv = __builtin_amdgcn_rcpf(den);
      #pragma unroll
      for (int cc = 0; cc < 5; ++cc) {
        const float cw = e[cc] * inv;
        #pragma unroll
        for (int jo = 0; jo < 4; ++jo)
          sacc[cc][k][jo] += cw * u[cc][k][jo];
      }
    }
  }
}

// lane map: oq = lane&3, ch = (lane>>2)&1, bl = lane>>3; thread owns
// b0 = btile*64 + wave*16 + bl*2 (+k), c = ch*5+cc, o = oq*4+jo.
// grid 768: xcd = bid&7, idx = bid>>3 (0..95); rtile = xcd*12 + idx%12,
// btile = idx/12. Each XCD owns 12 contiguous rtiles (720KB W + 2.4MB xt
// working set, L2-resident).
template<bool UNIFORM>
__global__ __launch_bounds__(256, 2) void acc_kernel(
    const float* __restrict__ xt, const float* __restrict__ W,
    const float* __restrict__ vsum, float* __restrict__ part)
{
  __shared__ float4 wbuf[2 * CG];   // 40 KB: two 4-slab chunks

  const int tid  = threadIdx.x;
  const int wave = tid >> 6;
  const int lane = tid & 63;
  const int oq   = lane & 3;
  const int ch   = (lane >> 2) & 1;
  const int bl   = lane >> 3;

  const int bid   = blockIdx.x;
  const int xcd   = bid & 7;
  const int idx   = bid >> 3;             // 0..95
  const int rtile = xcd * 12 + (idx % 12);
  const int btile = idx / 12;             // 0..7

  const int b0 = btile * 64 + wave * 16 + bl * 2;
  const int r0 = rtile * RCHB;

  auto stage = [&](int ci, int buf) {
    const float4* wc = reinterpret_cast<const float4*>(W)
                     + (size_t)(r0 + ci * CHUNK) * GRAN;
    float4* dst = &wbuf[buf * CG];
    #pragma unroll
    for (int s = 0; s < CHUNK; ++s) {
      dst[s * GRAN + swz(tid)] = wc[s * GRAN + tid];
      if (tid < GRAN - 256)
        dst[s * GRAN + swz(tid + 256)] = wc[s * GRAN + tid + 256];
    }
  };

  auto xload = [&](int r, float (&dst)[2][8]) {
    const float4* xp = reinterpret_cast<const float4*>(xt) + ((size_t)r * B_TOT + b0) * 2;
    #pragma unroll
    for (int k = 0; k < 2; ++k) {
      const float4 a = xp[2 * k], b = xp[2 * k + 1];
      dst[k][0] = a.x; dst[k][1] = a.y; dst[k][2] = a.z; dst[k][3] = a.w;
      dst[k][4] = b.x; dst[k][5] = b.y; dst[k][6] = b.z; dst[k][7] = b.w;
    }
  };

  // 8 swizzled LDS base pointers (granule units): ch*160 + oq*8 + (j ^ xv)
  const int xv = (ch << 2) | oq;
  const float4* A[8];
  #pragma unroll
  for (int j = 0; j < 8; ++j)
    A[j] = &wbuf[ch * 160 + oq * 8 + (j ^ xv)];

  float vf[5][2][4];
  if constexpr (!UNIFORM) {
    #pragma unroll
    for (int cc = 0; cc < 5; ++cc)
      #pragma unroll
      for (int k = 0; k < 2; ++k) {
        const float4 tv = *reinterpret_cast<const float4*>(
            &vsum[((b0 + k) * C_N + ch * 5 + cc) * O_N + oq * 4]);
        vf[cc][k][0] = tv.x; vf[cc][k][1] = tv.y; vf[cc][k][2] = tv.z; vf[cc][k][3] = tv.w;
      }
  }

  float sacc[5][2][4];
  #pragma unroll
  for (int cc = 0; cc < 5; ++cc)
    #pragma unroll
    for (int k = 0; k < 2; ++k)
      #pragma unroll
      for (int jo = 0; jo < 4; ++jo) sacc[cc][k][jo] = 0.0f;

  float xc[2][8], xn[2][8];
  stage(0, 0);
  xload(r0, xc);
  __syncthreads();

  #pragma unroll 1
  for (int ci = 0; ci < NCH; ++ci) {
    if (ci + 1 < NCH) stage(ci + 1, (ci + 1) & 1);
    const int sb = (ci & 1) * CG;
    #pragma unroll 2
    for (int rr = 0; rr < CHUNK; ++rr) {
      const int rl = ci * CHUNK + rr;
      const int rn = (rl + 1 < RCHB) ? rl + 1 : rl;
      xload(r0 + rn, xn);                 // prefetch next x under compute
      body<UNIFORM>(A, sb + rr * GRAN, xc, vf, sacc);
      #pragma unroll
      for (int k = 0; k < 2; ++k)
        #pragma unroll
        for (int i = 0; i < 8; ++i) xc[k][i] = xn[k][i];
    }
    __syncthreads();
  }

  // non-temporal partial stores: write-once stream, keep it out of L2
  const float scale = UNIFORM ? 0.1f : 1.0f;
  float* pb = part + (size_t)rtile * SEG;
  #pragma unroll
  for (int cc = 0; cc < 5; ++cc)
    #pragma unroll
    for (int k = 0; k < 2; ++k) {
      f32x4 v;
      v.x = sacc[cc][k][0] * scale; v.y = sacc[cc][k][1] * scale;
      v.z = sacc[cc][k][2] * scale; v.w = sacc[cc][k][3] * scale;
      __builtin_nontemporal_store(v, reinterpret_cast<f32x4*>(
          &pb[((b0 + k) * C_N + ch * 5 + cc) * O_N + oq * 4]));
    }
}

// reduce over rtiles + squash over O=16 per (b,c). grid = SEG/64 blocks.
// MODE 0: vsum = v ; MODE 1: vsum += v ; MODE 2: out = v
template<int MODE>
__global__ __launch_bounds__(256) void reduce_squash(
    const float* __restrict__ part, int nrt,
    float* __restrict__ vsum, float* __restrict__ out)
{
  __shared__ float lds[4][64];
  const int tid = threadIdx.x;
  const int l   = tid & 63;
  const int q   = tid >> 6;
  const int j   = blockIdx.x * 64 + l;
  const float* p = part + j;
  float sv = 0.0f;
  #pragma unroll 4
  for (int rt = q; rt < nrt; rt += 4) sv += __builtin_nontemporal_load(p + (size_t)rt * SEG);
  lds[q][l] = sv;
  __syncthreads();
  if (q == 0) {
    sv = lds[0][l] + lds[1][l] + lds[2][l] + lds[3][l];
    float sq = sv * sv;
    sq += __shfl_xor(sq, 1);
    sq += __shfl_xor(sq, 2);
    sq += __shfl_xor(sq, 4);
    sq += __shfl_xor(sq, 8);
    const float scale = sq / (1.0f + sq) * rsqrtf(sq + 1e-8f);
    const float v = scale * sv;
    if constexpr (MODE == 0)      vsum[j] = v;
    else if constexpr (MODE == 1) vsum[j] += v;
    else                          out[j] = v;
  }
}

extern "C" void kernel_launch(void* const* d_in, const int* in_sizes, int n_in,
                              void* d_out, int out_size, void* d_ws, size_t ws_size,
                              hipStream_t stream) {
  (void)in_sizes; (void)n_in; (void)out_size; (void)ws_size;
  const float* x = (const float*)d_in[0];
  const float* W = (const float*)d_in[1];
  float* out  = (float*)d_out;   // doubles as vsum; fully rewritten with v2
  float* part = (float*)d_ws;    // RT * SEG floats = 31.4 MB
  float* xt   = part + (size_t)RT * SEG;   // 18.9 MB (50.3 MB total, proven fit R6)

  const dim3 blk(256), accGrid(8 * RT), sqGrid(SEG / 64);

  hipLaunchKernelGGL(transpose_x, dim3((B_TOT * R_TOT) / 256), blk, 0, stream, x, xt);

  // iter 0: uniform coefficients (softmax of zeros)
  hipLaunchKernelGGL((acc_kernel<true>),  accGrid, blk, 0, stream, xt, W, out, part);
  hipLaunchKernelGGL((reduce_squash<0>),  sqGrid,  blk, 0, stream, part, RT, out, out);  // vsum = v0
  // iter 1
  hipLaunchKernelGGL((acc_kernel<false>), accGrid, blk, 0, stream, xt, W, out, part);
  hipLaunchKernelGGL((reduce_squash<1>),  sqGrid,  blk, 0, stream, part, RT, out, out);  // vsum = v0+v1
  // iter 2
  hipLaunchKernelGGL((acc_kernel<false>), accGrid, blk, 0, stream, xt, W, out, part);
  hipLaunchKernelGGL((reduce_squash<2>),  sqGrid,  blk, 0, stream, part, RT, out, out);  // out = v2
}